// Round 3
// baseline (272.255 us; speedup 1.0000x reference)
//
#include <hip/hip_runtime.h>

#define THREADS 256

__device__ __forceinline__ float fast_sigmoid(float v) {
    float e = __expf(-v);
    return __builtin_amdgcn_rcpf(1.0f + e);
}

// 1 sample/thread, NO LDS, pipelined load-then-compute.
//
// Round-0 rocprof evidence: VGPR_Count=44 -> compiler sank the 81 pix loads
// to just-before-use (many shallow ~800cy vmcnt windows); VALUBusy 27%;
// L3-warm replays no faster than cold => latency-stall-bound, not BW-bound.
//
// Fix: per-group liveness fences. All 81 loads are written in program order
// up front; before group G's compute, an empty asm forces that group's 27
// inputs to be VGPR-resident. The compiler may keep all loads up front (one
// deep window) or sink group G+1's loads under group G's ~1500cy compute
// (3-stage pipeline, ~60 VGPRs peak). Both schedules replace the shallow
// fragmented windows that caused the stalls. Peak pressure stays well under
// the 128-VGPR cap of __launch_bounds__(256,4).
__global__ __launch_bounds__(THREADS, 4) void olcnn_kernel(
    const float* __restrict__ x,
    const float* __restrict__ Wc, const float* __restrict__ bc,
    const float* __restrict__ Wh, const float* __restrict__ bh,
    const float* __restrict__ Wm, const float* __restrict__ bm,
    const float* __restrict__ Wo, const float* __restrict__ bo,
    float* __restrict__ out)
{
    const int s = blockIdx.x * THREADS + threadIdx.x;   // lane-contiguous samples
    const float* xs = x + s * 81;

    // Whole sample, program-order. Consecutive lanes read consecutive 324-B
    // runs -> wave footprint contiguous, every line fully consumed.
    float pix[81];
    #pragma unroll
    for (int i = 0; i < 81; ++i) pix[i] = xs[i];

    float res[4];

    #pragma unroll
    for (int G = 0; G < 3; ++G) {
        // Liveness fence: group G's 27 inputs must be in VGPRs HERE. Forbids
        // the compiler from fragmenting this group's loads into shallow
        // just-before-use windows inside the compute below.
        #pragma unroll
        for (int i = 0; i < 27; ++i) asm volatile("" : "+v"(pix[G * 27 + i]));

        float hbuf[9];
        #pragma unroll
        for (int j = 0; j < 3; ++j) {              // conv patch g = (G, j)
            const int g = G * 3 + j;
            float feat[9];
            #pragma unroll
            for (int k = 0; k < 9; ++k) {          // 9 independent chains -> ILP
                float acc = bc[g * 9 + k];
                #pragma unroll
                for (int pr = 0; pr < 3; ++pr)
                    #pragma unroll
                    for (int pc = 0; pc < 3; ++pc)
                        acc = fmaf(pix[G * 27 + pr * 9 + j * 3 + pc],
                                   Wc[(g * 9 + k) * 9 + pr * 3 + pc], acc);
                feat[k] = fast_sigmoid(acc);
            }
            #pragma unroll
            for (int n = 0; n < 3; ++n) {
                float acc = bh[g * 3 + n];
                #pragma unroll
                for (int p = 0; p < 9; ++p)
                    acc = fmaf(feat[p], Wh[(g * 3 + n) * 9 + p], acc);
                hbuf[j * 3 + n] = fast_sigmoid(acc);
            }
        }

        float m[4];
        #pragma unroll
        for (int n = 0; n < 4; ++n) {
            float acc = bm[G * 4 + n];
            #pragma unroll
            for (int p = 0; p < 9; ++p)
                acc = fmaf(hbuf[p], Wm[(G * 4 + n) * 9 + p], acc);
            m[n] = fast_sigmoid(acc);
        }

        // outputs reading middle group G (c % 3 == G): c = G, plus c = 3 @ G = 0
        {
            float acc = bo[G];
            #pragma unroll
            for (int p = 0; p < 4; ++p)
                acc = fmaf(m[p], Wo[G * 4 + p], acc);
            res[G] = acc;
        }
        if (G == 0) {
            float acc = bo[3];
            #pragma unroll
            for (int p = 0; p < 4; ++p)
                acc = fmaf(m[p], Wo[3 * 4 + p], acc);
            res[3] = acc;
        }
    }

    float4 o;
    o.x = res[0]; o.y = res[1]; o.z = res[2]; o.w = res[3];
    ((float4*)out)[s] = o;                         // coalesced 16B/lane store
}

extern "C" void kernel_launch(void* const* d_in, const int* in_sizes, int n_in,
                              void* d_out, int out_size, void* d_ws, size_t ws_size,
                              hipStream_t stream) {
    const float* x  = (const float*)d_in[0];
    const float* Wc = (const float*)d_in[1];
    const float* bc = (const float*)d_in[2];
    const float* Wh = (const float*)d_in[3];
    const float* bh = (const float*)d_in[4];
    const float* Wm = (const float*)d_in[5];
    const float* bm = (const float*)d_in[6];
    const float* Wo = (const float*)d_in[7];
    const float* bo = (const float*)d_in[8];
    float* out = (float*)d_out;

    const int B = in_sizes[0] / 81;                // 524288
    const int blocks = B / THREADS;                // 2048 (exact)
    olcnn_kernel<<<blocks, THREADS, 0, stream>>>(x, Wc, bc, Wh, bh, Wm, bm,
                                                 Wo, bo, out);
}